// Round 16
// baseline (780.878 us; speedup 1.0000x reference)
//
#include <hip/hip_runtime.h>
#include <hip/hip_bf16.h>
#include <stdint.h>

#define B_SZ  16
#define S_SZ  2048
#define D_SZ  1024
#define FF_SZ 4096
#define DT_SZ 512

typedef __bf16 bf16x8 __attribute__((ext_vector_type(8)));
typedef float  f32x16 __attribute__((ext_vector_type(16)));
typedef short  short8 __attribute__((ext_vector_type(8)));

__device__ __forceinline__ short f2bf(float x) {
    union { float f; uint32_t u; } v; v.f = x;
    uint32_t r = (v.u + 0x7fffu + ((v.u >> 16) & 1u)) >> 16;  // RNE
    return (short)(uint16_t)r;
}

// ---------------- cast f32 -> bf16, 8 elems/thread ----------------
__global__ void cast_x_kernel(const float* __restrict__ src, short* __restrict__ dst, int n8) {
    int i = blockIdx.x * 256 + threadIdx.x;
    if (i >= n8) return;
    const float4* s4 = reinterpret_cast<const float4*>(src);
    float4 a = s4[2 * i], b = s4[2 * i + 1];
    short8 v;
    v[0] = f2bf(a.x); v[1] = f2bf(a.y); v[2] = f2bf(a.z); v[3] = f2bf(a.w);
    v[4] = f2bf(b.x); v[5] = f2bf(b.y); v[6] = f2bf(b.z); v[7] = f2bf(b.w);
    reinterpret_cast<short8*>(dst)[i] = v;
}

// ---------------- transpose + cast: src f32 [R][C] -> dst bf16 [C][R] ----------------
__global__ void transpose_cast_kernel(const float* __restrict__ src, short* __restrict__ dst,
                                      int R, int C) {
    __shared__ float tile[32][33];
    int c0 = blockIdx.x * 32, r0 = blockIdx.y * 32;
    int tx = threadIdx.x, ty = threadIdx.y;   // 32 x 8
#pragma unroll
    for (int i = 0; i < 32; i += 8)
        tile[ty + i][tx] = src[(size_t)(r0 + ty + i) * C + (c0 + tx)];
    __syncthreads();
#pragma unroll
    for (int i = 0; i < 32; i += 8)
        dst[(size_t)(c0 + ty + i) * R + (r0 + tx)] = f2bf(tile[tx][ty + i]);
}

// =====================================================================
// 128x128-tile bf16 GEMM — r13 structure (cross-block overlap, 4 blk/CU)
// with 32x32x16 MFMA: HALF the MFMA instruction count per FLOP.
// r13 PMC: MfmaUtil 41 + VALUBusy 50 ~= 90% combined SIMD issue ->
// issue-saturation hypothesis; 32x32x16 frees 16 issue slots/wave/step
// and 17% matrix-pipe time (8.07 cyc/32K-FLOP vs 4.85/16K).
//   * 4 waves (2x2), per-wave 64x64 via 2x2 acc of 32x32 (64 VGPR, same)
//   * BK=64, single 32 KB LDS buffer, plain __syncthreads()
//   * same staging (global_load_lds, inverse-swizzled source)
//   * swizzle/operand/D layouts r11-ref-verified
// =====================================================================

#define GLOAD(srcp, dstofs)                                                   \
    __builtin_amdgcn_global_load_lds(                                         \
        (__attribute__((address_space(1))) void*)(srcp),                      \
        (__attribute__((address_space(3))) void*)(ldsb + (dstofs)), 16, 0, 0)

template <bool GELU_BF16>
__global__ __launch_bounds__(256, 4)
void gemm128_kernel(const short* __restrict__ A, const short* __restrict__ Bt,
                    void* __restrict__ Cout, int M, int N, int K) {
    __shared__ char lds[32768];    // A[128 rows x 128B] @0, B @16384
    char* ldsb = &lds[0];

    const int tid = threadIdx.x;
    const int w   = tid >> 6;      // 0..3
    const int l   = tid & 63;
    const int wm  = w >> 1;        // 0..1
    const int wn  = w & 1;         // 0..1
    const int l31 = l & 31;
    const int lh  = l >> 5;        // 0..1

    // XCD-bijective block swizzle; bn-fast so consecutive blocks share the A-tile
    const int nwg = gridDim.x;
    int swzw = blockIdx.x;
    if ((nwg & 7) == 0) swzw = (swzw & 7) * (nwg >> 3) + (swzw >> 3);
    const int NB = N >> 7;
    const int bm = swzw / NB, bn = swzw % NB;
    const int m0 = bm << 7, n0 = bn << 7;

    // ---- swizzled ds_read byte offsets for ks=0 (ks -> off ^ (ks<<5)) ----
    // logical = r*128 + ks*32 + lh*16 ; phys slot = (2ks+lh) ^ (r&7)
    int offA0[2], offB0[2];
#pragma unroll
    for (int mi = 0; mi < 2; ++mi) {
        const int r = wm * 64 + mi * 32 + l31;
        offA0[mi] = r * 128 + ((lh ^ (r & 7)) << 4);
    }
#pragma unroll
    for (int ni = 0; ni < 2; ++ni) {
        const int r = wn * 64 + ni * 32 + l31;
        offB0[ni] = 16384 + r * 128 + ((lh ^ (r & 7)) << 4);
    }

    // ---- staging sources (inverse-swizzled global, linear LDS dest) ----
    const short *gA[4], *gB[4];
#pragma unroll
    for (int j = 0; j < 4; ++j) {
        const int X = j * 4096 + tid * 16;
        const int P = X ^ (((X >> 7) & 7) << 4);
        const int r = P >> 7, c = (P & 127) >> 1;
        gA[j] = A  + (size_t)(m0 + r) * K + c;
        gB[j] = Bt + (size_t)(n0 + r) * K + c;
    }

    f32x16 acc[2][2];
#pragma unroll
    for (int mi = 0; mi < 2; ++mi)
#pragma unroll
        for (int ni = 0; ni < 2; ++ni)
            acc[mi][ni] = (f32x16)(0.f);

    const int NT = K >> 6;         // K-steps of 64 (16 or 64 here)

    for (int t = 0; t < NT; ++t) {
        __syncthreads();           // WAR: previous step's reads done
#pragma unroll
        for (int j = 0; j < 4; ++j) {
            GLOAD(gA[j] + (size_t)t * 64,         j * 4096 + tid * 16);
            GLOAD(gB[j] + (size_t)t * 64, 16384 + j * 4096 + tid * 16);
        }
        __syncthreads();           // compiler drains vmcnt before barrier
#pragma unroll
        for (int ks = 0; ks < 4; ++ks) {
            bf16x8 a[2], b[2];
#pragma unroll
            for (int mi = 0; mi < 2; ++mi)
                a[mi] = *reinterpret_cast<const bf16x8*>(ldsb + (offA0[mi] ^ (ks << 5)));
#pragma unroll
            for (int ni = 0; ni < 2; ++ni)
                b[ni] = *reinterpret_cast<const bf16x8*>(ldsb + (offB0[ni] ^ (ks << 5)));
#pragma unroll
            for (int mi = 0; mi < 2; ++mi)
#pragma unroll
                for (int ni = 0; ni < 2; ++ni)
                    acc[mi][ni] = __builtin_amdgcn_mfma_f32_32x32x16_bf16(
                        a[mi], b[ni], acc[mi][ni], 0, 0, 0);
        }
    }

    // epilogue — 32x32 D layout (m74/m101, r11-verified): col = lane&31,
    // row = (reg&3) + 8*(reg>>2) + 4*(lane>>5)
    if constexpr (GELU_BF16) {
        short* C = reinterpret_cast<short*>(Cout);
#pragma unroll
        for (int mi = 0; mi < 2; ++mi) {
            const int rb = m0 + wm * 64 + mi * 32 + 4 * lh;
#pragma unroll
            for (int ni = 0; ni < 2; ++ni) {
                const int col = n0 + wn * 64 + ni * 32 + l31;
#pragma unroll
                for (int reg = 0; reg < 16; ++reg) {
                    const int row = rb + (reg & 3) + 8 * (reg >> 2);
                    float x = acc[mi][ni][reg];
                    float u = 0.7978845608028654f * (x + 0.044715f * x * x * x);
                    float g = x / (1.f + __expf(-2.f * u));
                    C[(size_t)row * N + col] = f2bf(g);
                }
            }
        }
    } else {
        float* C = reinterpret_cast<float*>(Cout);
#pragma unroll
        for (int mi = 0; mi < 2; ++mi) {
            const int rb = m0 + wm * 64 + mi * 32 + 4 * lh;
#pragma unroll
            for (int ni = 0; ni < 2; ++ni) {
                const int col = n0 + wn * 64 + ni * 32 + l31;
#pragma unroll
                for (int reg = 0; reg < 16; ++reg) {
                    const int row = rb + (reg & 3) + 8 * (reg >> 2);
                    C[(size_t)row * N + col] = acc[mi][ni][reg];
                }
            }
        }
    }
}

// ---------------- intervention: out[b, eot[b], 0:512] = row[0:512] @ Wrot @ Winv ----------------
__global__ void intervention_kernel(const float* __restrict__ Wrot, const float* __restrict__ Winv,
                                    const int* __restrict__ eot, float* __restrict__ out) {
    __shared__ float tgt[DT_SZ];
    __shared__ float tmp[DT_SZ];
    const int b = blockIdx.x;
    const int j = threadIdx.x;
    float* row = out + ((size_t)b * S_SZ + eot[b]) * D_SZ;
    tgt[j] = row[j];                      // ST=0 slice
    __syncthreads();
    float s = 0.f;
#pragma unroll 8
    for (int i = 0; i < DT_SZ; ++i) s = fmaf(tgt[i], Wrot[(size_t)i * DT_SZ + j], s);
    tmp[j] = s;
    __syncthreads();
    float s2 = 0.f;
#pragma unroll 8
    for (int i = 0; i < DT_SZ; ++i) s2 = fmaf(tmp[i], Winv[(size_t)i * DT_SZ + j], s2);
    row[j] = s2;
}

extern "C" void kernel_launch(void* const* d_in, const int* in_sizes, int n_in,
                              void* d_out, int out_size, void* d_ws, size_t ws_size,
                              hipStream_t stream) {
    const float* hidden = (const float*)d_in[0];
    const float* W1     = (const float*)d_in[1];
    const float* W2     = (const float*)d_in[2];
    const float* Wrot   = (const float*)d_in[3];
    const float* Winv   = (const float*)d_in[4];
    const int*   eot    = (const int*)d_in[5];
    float* out = (float*)d_out;

    const int M = B_SZ * S_SZ;   // 32768

    // ws layout: W1t (FF x D bf16) | W2t (D x FF bf16) | Xbf chunk | C1 chunk
    short* W1t = (short*)d_ws;
    short* W2t = W1t + (size_t)FF_SZ * D_SZ;
    short* Xbf = W2t + (size_t)FF_SZ * D_SZ;
    const size_t fixed_bytes = 2ull * (size_t)FF_SZ * D_SZ * sizeof(short);  // 16 MiB
    const size_t per_row = (size_t)D_SZ * 2 + (size_t)FF_SZ * 2;             // 10240 B
    size_t rem = ws_size > fixed_bytes ? ws_size - fixed_bytes : 0;
    int Mc = (int)(rem / per_row);
    Mc = (Mc / 512) * 512;       // keeps every grid a multiple of 8
    if (Mc < 512) Mc = 512;
    if (Mc > M) Mc = M;
    short* C1 = Xbf + (size_t)Mc * D_SZ;

    transpose_cast_kernel<<<dim3(FF_SZ / 32, D_SZ / 32), dim3(32, 8), 0, stream>>>(W1, W1t, D_SZ, FF_SZ);
    transpose_cast_kernel<<<dim3(D_SZ / 32, FF_SZ / 32), dim3(32, 8), 0, stream>>>(W2, W2t, FF_SZ, D_SZ);

    for (int ms = 0; ms < M; ms += Mc) {
        const int mc = (M - ms < Mc) ? (M - ms) : Mc;   // multiple of 512
        const int n8 = mc * D_SZ / 8;
        cast_x_kernel<<<(n8 + 255) / 256, 256, 0, stream>>>(hidden + (size_t)ms * D_SZ, Xbf, n8);
        gemm128_kernel<true ><<<dim3((mc / 128) * (FF_SZ / 128)), 256, 0, stream>>>(
            Xbf, W1t, C1, mc, FF_SZ, D_SZ);
        gemm128_kernel<false><<<dim3((mc / 128) * (D_SZ / 128)), 256, 0, stream>>>(
            C1, W2t, out + (size_t)ms * D_SZ, mc, D_SZ, FF_SZ);
    }
    intervention_kernel<<<B_SZ, DT_SZ, 0, stream>>>(Wrot, Winv, eot, out);
}